// Round 14
// baseline (44.209 us; speedup 1.0000x reference)
//
#include <hip/hip_runtime.h>
#include <math.h>

#define HH 512
#define WW 512
#define YS 132   // Y plane row stride (words); %32=4 -> spread banks
#define CS 68    // chroma plane row stride
#define SG 68    // scratch group stride (words); %32=4

typedef float f2 __attribute__((ext_vector_type(2)));
typedef float f4 __attribute__((ext_vector_type(4)));

static __device__ __forceinline__ f4 vclamp01x255(f4 v) {
    f4 z = 0.f, one = 1.f;
    return __builtin_elementwise_max(__builtin_elementwise_min(v, one), z) * 255.f;
}

// LDS-producer/consumer barrier that does NOT drain vmcnt: global loads
// issued before it stay in flight (m201/m214 pattern). lgkmcnt(0) makes the
// LDS writes visible; "memory" clobber pins compiler-level LDS ordering and
// prevents global loads from sinking across (asm may write memory).
static __device__ __forceinline__ void lds_barrier() {
    asm volatile("s_waitcnt lgkmcnt(0)\n\ts_barrier" ::: "memory");
}

__device__ __constant__ float YTAB[64] = {
    16,11,10,16,24,40,51,61,
    12,12,14,19,26,58,60,55,
    14,13,16,24,40,57,69,56,
    14,17,22,29,51,87,80,62,
    18,22,37,56,68,109,103,77,
    24,35,55,64,81,104,113,92,
    49,64,78,87,103,121,120,101,
    72,92,95,98,112,100,103,99};
__device__ __constant__ float CTAB[64] = {
    17,18,24,47,99,99,99,99,
    18,21,26,66,99,99,99,99,
    24,26,56,99,99,99,99,99,
    47,66,99,99,99,99,99,99,
    99,99,99,99,99,99,99,99,
    99,99,99,99,99,99,99,99,
    99,99,99,99,99,99,99,99,
    99,99,99,99,99,99,99,99};

// One workgroup = TWO 128x16 tiles, software-pipelined: tile1's global loads
// issue before tile0's compute and their latency hides under it. Per tile:
// 32 Y + 8 Cb + 8 Cr blocks = 48 groups = 6 waves x 8. Lane j of a group
// holds column j of its 8x8 block; 4 packed fmaf-chain matrix passes with
// basis wave-uniform; 3 small LDS transposes. Bit-critical pre-round math
// identical to verified R8/R10-R13:
//  - color: left-assoc mul/add, NO fma; chroma mean paired (s01+s23)/4
//  - DCT: two ascending-k fmaf chains (BLAS sgemm semantics), fp32 T1
//  - quantize: IEEE fp32 scalar div by qt, rintf (half-even), cube fp32
// Post-round relaxed (*INV255, nontemporal stores).
__global__ __launch_bounds__(384) void jpeg_fused(const float* __restrict__ in,
                                                  float* __restrict__ out)
{
#pragma clang fp contract(off)
    __shared__ float Yp[16][YS];
    __shared__ float Cbp[8][CS];
    __shared__ float Crp[8][CS];
    __shared__ float Ab[64];
    __shared__ float QY[64], QC[64];
    __shared__ float Scr[6][8 * SG];

    const int tid  = threadIdx.x;
    const int wid  = tid >> 6;
    const int lane = tid & 63;
    const int g    = lane >> 3;        // block-group within wave
    const int j    = lane & 7;         // role index within block

    const int bid   = blockIdx.x;
    const int b     = bid >> 6;        // 64 WGs per image (32 strips x 2 halves)
    const int strip = (bid >> 1) & 31;
    const int half  = bid & 1;
    const int h0    = strip * 16;
    const int w0    = half * 256;      // this WG covers cols w0..w0+255
    const size_t plane = (size_t)HH * WW;

    // ---- init: basis (np-exact: int mult, fp64 pi-mult/div, fp64 cos, fp32
    // cast) + quant tables into LDS
    if (tid < 64) {
        int x = tid >> 3, u = tid & 7;
        double arg = (double)((2 * x + 1) * u) * 3.14159265358979323846 / 16.0;
        Ab[tid] = (float)cos(arg);
        QY[tid] = YTAB[tid];
        QC[tid] = CTAB[tid];
    }

    // staging/output coords (valid for tid<256)
    const int rowp = tid >> 5;         // 0..7 (row pair)
    const int pc   = (tid & 31) * 4;   // 0..124
    const int pr   = rowp * 2;
    const int qc   = (tid & 31) * 2;

    const bool isY = (wid < 4);
    float* scr = &Scr[wid][0];
    f2 As2[32];                        // basis pairs, filled after B1

    // ---- lambdas -------------------------------------------------------
    auto loadT = [&](f4* L, int tw) {
        size_t base = ((size_t)b * 3 * HH + (size_t)(h0 + pr)) * WW + (tw + pc);
        L[0] = *(const f4*)(in + base);
        L[1] = *(const f4*)(in + base + WW);
        L[2] = *(const f4*)(in + base + plane);
        L[3] = *(const f4*)(in + base + plane + WW);
        L[4] = *(const f4*)(in + base + 2 * plane);
        L[5] = *(const f4*)(in + base + 2 * plane + WW);
    };

    auto stageT = [&](const f4* L) {
#pragma clang fp contract(off)
        f4 r0 = vclamp01x255(L[0]), r1 = vclamp01x255(L[1]);
        f4 g0 = vclamp01x255(L[2]), g1 = vclamp01x255(L[3]);
        f4 b0 = vclamp01x255(L[4]), b1 = vclamp01x255(L[5]);
        // noblas matmul: left-assoc, separate rn mul/add (no fma), elementwise
        f4 y0  = ((r0 * 0.299f)     + (g0 * 0.587f))     + (b0 * 0.114f);
        f4 y1  = ((r1 * 0.299f)     + (g1 * 0.587f))     + (b1 * 0.114f);
        f4 cb0 = ((r0 * -0.168736f) + (g0 * -0.331264f)) + (b0 * 0.5f);
        f4 cb1 = ((r1 * -0.168736f) + (g1 * -0.331264f)) + (b1 * 0.5f);
        f4 cr0 = ((r0 * 0.5f)       + (g0 * -0.418688f)) + (b0 * -0.081312f);
        f4 cr1 = ((r1 * 0.5f)       + (g1 * -0.418688f)) + (b1 * -0.081312f);
        cb0 = cb0 + 128.f; cb1 = cb1 + 128.f;   // +SHIFT1 separate rn add
        cr0 = cr0 + 128.f; cr1 = cr1 + 128.f;
        y0 = y0 - 128.f;  y1 = y1 - 128.f;      // channel does blocks-128
        *(f4*)&Yp[pr][pc]     = y0;
        *(f4*)&Yp[pr + 1][pc] = y1;
        // np multi-axis mean: paired (p00+p01)+(p10+p11), true-div by 4
        {
            float s01a = cb0.x + cb0.y, s23a = cb1.x + cb1.y;
            float s01b = cb0.z + cb0.w, s23b = cb1.z + cb1.w;
            *(float2*)&Cbp[rowp][qc] =
                make_float2((s01a + s23a) / 4.0f, (s01b + s23b) / 4.0f);
        }
        {
            float s01a = cr0.x + cr0.y, s23a = cr1.x + cr1.y;
            float s01b = cr0.z + cr0.w, s23b = cr1.z + cr1.w;
            *(float2*)&Crp[rowp][qc] =
                make_float2((s01a + s23a) / 4.0f, (s01b + s23b) / 4.0f);
        }
    };

    auto computeT = [&]() {
#pragma clang fp contract(off)
        // load X columns (lane j = column j of its block)
        float X[8];
        if (isY) {
            int blk = wid * 8 + g;
            int by = blk >> 4, bx = blk & 15;
#pragma unroll
            for (int x = 0; x < 8; ++x) X[x] = Yp[by * 8 + x][bx * 8 + j];
        } else {
            const float (*Cp)[CS] = (wid == 4) ? Cbp : Crp;
#pragma unroll
            for (int x = 0; x < 8; ++x) X[x] = Cp[x][g * 8 + j] - 128.f;
        }
        // pass1 (contract x): T1[y=j][u], ascending-x fmaf chains, packed
        f2 Tv[4];
#pragma unroll
        for (int m = 0; m < 4; ++m) {
            f2 a = {0.f, 0.f};
#pragma unroll
            for (int x = 0; x < 8; ++x) {
                f2 xx = {X[x], X[x]};
                a = __builtin_elementwise_fma(xx, As2[x * 4 + m], a);
            }
            Tv[m] = a;
        }
#pragma unroll
        for (int m = 0; m < 4; ++m) {
            scr[g * SG + (2 * m) * 8 + j]     = Tv[m][0];
            scr[g * SG + (2 * m + 1) * 8 + j] = Tv[m][1];
        }
        float Tt[8];
        {
            float4 a = *(const float4*)&scr[g * SG + j * 8];
            float4 c = *(const float4*)&scr[g * SG + j * 8 + 4];
            Tt[0] = a.x; Tt[1] = a.y; Tt[2] = a.z; Tt[3] = a.w;
            Tt[4] = c.x; Tt[5] = c.y; Tt[6] = c.z; Tt[7] = c.w;
        }
        // pass2 (contract y): raw[u=j][v], ascending-y packed chains
        float R[8];
#pragma unroll
        for (int m = 0; m < 4; ++m) {
            f2 a = {0.f, 0.f};
#pragma unroll
            for (int y = 0; y < 8; ++y) {
                f2 tt = {Tt[y], Tt[y]};
                a = __builtin_elementwise_fma(tt, As2[y * 4 + m], a);
            }
            R[2 * m] = a[0]; R[2 * m + 1] = a[1];
        }
        // quantize row u=j (bit-critical, scalar div/rintf), dequant, *alpha2
        float qt[8];
        {
            const float* QT = isY ? QY : QC;
            float4 a = *(const float4*)&QT[j * 8];
            float4 c = *(const float4*)&QT[j * 8 + 4];
            qt[0] = a.x; qt[1] = a.y; qt[2] = a.z; qt[3] = a.w;
            qt[4] = c.x; qt[5] = c.y; qt[6] = c.z; qt[7] = c.w;
        }
        const float RC = 0.70710678118654752440f;
        float au = (j == 0) ? RC : 1.0f;
        float G[8];
#pragma unroll
        for (int v = 0; v < 8; ++v) {
            float av    = (v == 0) ? RC : 1.0f;
            float a2    = au * av;            // ALPHA2 fp32 product
            float scale = a2 * 0.25f;         // _SCALE
            float dct   = scale * R[v];
            float xq    = dct / qt[v];        // IEEE fp32 divide (bit-critical)
            float rd    = rintf(xq);          // half-to-even
            float d     = xq - rd;
            float cube  = (d * d) * d;
            float qq    = rd + cube;
            float deq   = qq * qt[v];
            G[v] = deq * a2;
        }
#pragma unroll
        for (int v = 0; v < 8; ++v) scr[g * SG + v * 8 + j] = G[v];
        float Gt[8];
        {
            float4 a = *(const float4*)&scr[g * SG + j * 8];
            float4 c = *(const float4*)&scr[g * SG + j * 8 + 4];
            Gt[0] = a.x; Gt[1] = a.y; Gt[2] = a.z; Gt[3] = a.w;
            Gt[4] = c.x; Gt[5] = c.y; Gt[6] = c.z; Gt[7] = c.w;
        }
        // IDCT pass1 (contract u): T2[x][v=j], packed over x pairs
        f2 T2v[4];
#pragma unroll
        for (int m = 0; m < 4; ++m) {
            f2 a = {0.f, 0.f};
#pragma unroll
            for (int u = 0; u < 8; ++u) {
                f2 gg = {Gt[u], Gt[u]};
                a = __builtin_elementwise_fma(gg, As2[u * 4 + m], a);
            }
            T2v[m] = a;
        }
#pragma unroll
        for (int m = 0; m < 4; ++m) {
            scr[g * SG + (2 * m) * 8 + j]     = T2v[m][0];
            scr[g * SG + (2 * m + 1) * 8 + j] = T2v[m][1];
        }
        float T2t[8];
        {
            float4 a = *(const float4*)&scr[g * SG + j * 8];
            float4 c = *(const float4*)&scr[g * SG + j * 8 + 4];
            T2t[0] = a.x; T2t[1] = a.y; T2t[2] = a.z; T2t[3] = a.w;
            T2t[4] = c.x; T2t[5] = c.y; T2t[6] = c.z; T2t[7] = c.w;
        }
        // IDCT pass2 (contract v): out[x=j][y] = 0.25*sum + 128, packed
        float O[8];
#pragma unroll
        for (int m = 0; m < 4; ++m) {
            f2 a = {0.f, 0.f};
#pragma unroll
            for (int v = 0; v < 8; ++v) {
                f2 tt = {T2t[v], T2t[v]};
                a = __builtin_elementwise_fma(tt, As2[v * 4 + m], a);
            }
            a = (a * 0.25f) + 128.f;
            O[2 * m] = a[0]; O[2 * m + 1] = a[1];
        }
        // write back in place (block regions disjoint)
        if (isY) {
            int blk = wid * 8 + g;
            int by = blk >> 4, bx = blk & 15;
            *(float4*)&Yp[by * 8 + j][bx * 8]     = make_float4(O[0], O[1], O[2], O[3]);
            *(float4*)&Yp[by * 8 + j][bx * 8 + 4] = make_float4(O[4], O[5], O[6], O[7]);
        } else {
            float (*Cp)[CS] = (wid == 4) ? Cbp : Crp;
            *(float4*)&Cp[j][g * 8]     = make_float4(O[0], O[1], O[2], O[3]);
            *(float4*)&Cp[j][g * 8 + 4] = make_float4(O[4], O[5], O[6], O[7]);
        }
    };

    auto outputT = [&](int tw) {
#pragma clang fp contract(off)
        const float INV255 = 1.0f / 255.0f;
        f4 ya = *(const f4*)&Yp[pr][pc];
        f4 yb = *(const f4*)&Yp[pr + 1][pc];
        float cb0 = Cbp[rowp][qc]     - 128.f;   // +SHIFT2 separate add
        float cb1 = Cbp[rowp][qc + 1] - 128.f;
        float cr0 = Crp[rowp][qc]     - 128.f;
        float cr1 = Crp[rowp][qc + 1] - 128.f;
        f4 cbm = {cb0, cb0, cb1, cb1};
        f4 crm = {cr0, cr0, cr1, cr1};
        f4 z = 0.f, m255 = 255.f;
#pragma unroll
        for (int row = 0; row < 2; ++row) {
            f4 yy = row ? yb : ya;
            f4 rv = yy + (crm * 1.402f);
            f4 gv = (yy + (cbm * -0.344136f)) + (crm * -0.714136f);
            f4 bv = yy + (cbm * 1.772f);
            rv = __builtin_elementwise_max(__builtin_elementwise_min(rv, m255), z) * INV255;
            gv = __builtin_elementwise_max(__builtin_elementwise_min(gv, m255), z) * INV255;
            bv = __builtin_elementwise_max(__builtin_elementwise_min(bv, m255), z) * INV255;
            size_t base = ((size_t)b * 3 * HH + (size_t)(h0 + pr + row)) * WW + (tw + pc);
            __builtin_nontemporal_store(rv, (f4*)(out + base));
            __builtin_nontemporal_store(gv, (f4*)(out + base + plane));
            __builtin_nontemporal_store(bv, (f4*)(out + base + 2 * plane));
        }
    };

    // ---- pipelined 2-tile schedule --------------------------------------
    f4 L0[6], L1[6];
    if (tid < 256) {
        loadT(L0, w0);            // tile 0 loads (exposed; kernel start)
        stageT(L0);               // convert + LDS stage tile 0
        loadT(L1, w0 + 128);      // tile 1 loads: IN FLIGHT across barriers
    }
    lds_barrier();                // B1: stage-t0 + tables visible (vmcnt live)

    // basis pairs -> wave-uniform f2 (SGPR pairs via readfirstlane)
#pragma unroll
    for (int k = 0; k < 32; ++k) {
        As2[k][0] = __int_as_float(__builtin_amdgcn_readfirstlane(__float_as_int(Ab[2 * k])));
        As2[k][1] = __int_as_float(__builtin_amdgcn_readfirstlane(__float_as_int(Ab[2 * k + 1])));
    }

    computeT();                   // tile 0 (t1 loads land underneath)
    lds_barrier();                // B2
    if (tid < 256) {
        outputT(w0);              // reads exactly its own stage cells...
        stageT(L1);               // ...then overwrites those same cells
    }
    lds_barrier();                // B3
    computeT();                   // tile 1
    lds_barrier();                // B4
    if (tid < 256) outputT(w0 + 128);
}

extern "C" void kernel_launch(void* const* d_in, const int* in_sizes, int n_in,
                              void* d_out, int out_size, void* d_ws, size_t ws_size,
                              hipStream_t stream)
{
    const float* x = (const float*)d_in[0];
    float* o = (float*)d_out;
    int batch  = in_sizes[0] / (3 * HH * WW);        // 32
    int blocks = batch * 32 * 2;                     // 2048 (2 tiles per WG)
    jpeg_fused<<<blocks, 384, 0, stream>>>(x, o);
}